// Round 6
// baseline (264.955 us; speedup 1.0000x reference)
//
#include <hip/hip_runtime.h>
#include <hip/hip_bf16.h>
#include <math.h>

typedef __attribute__((ext_vector_type(4))) float f32x4;
typedef __attribute__((ext_vector_type(8))) short bf16x8;
typedef unsigned short u16;
typedef unsigned int u32;

typedef f32x4  __attribute__((may_alias)) f32x4a;
typedef bf16x8 __attribute__((may_alias)) bf16x8a;
typedef uint2  __attribute__((may_alias)) uint2a;

__device__ __forceinline__ u16 bfbits(float f) {
  union { __hip_bfloat16 h; u16 u; } cv;
  cv.h = __float2bfloat16(f);
  return cv.u;
}
__device__ __forceinline__ float rcp_r(float x)  { return __builtin_amdgcn_rcpf(x); }
__device__ __forceinline__ float sqrt_r(float x) { return __builtin_amdgcn_sqrtf(x); }
__device__ __forceinline__ float log2_r(float x) { return __builtin_amdgcn_logf(x); }
__device__ __forceinline__ float exp2_r(float x) { return __builtin_amdgcn_exp2f(x); }
__device__ __forceinline__ float rsq_r(float x)  { return __builtin_amdgcn_rsqf(x); }
__device__ __forceinline__ u32 cvt_pk_bf16(float lo, float hi) {
  u32 r;
  asm("v_cvt_pk_bf16_f32 %0, %1, %2" : "=v"(r) : "v"(lo), "v"(hi));
  return r;
}
typedef const __attribute__((address_space(1))) unsigned int* gas_t;
typedef __attribute__((address_space(3))) unsigned int* las_t;
__device__ __forceinline__ void gload_lds16(const u16* g, u16* l) {
  __builtin_amdgcn_global_load_lds((gas_t)g, (las_t)l, 16, 0, 0);
}

// ---------------- weight fp32 -> bf16 ----------------
__global__ __launch_bounds__(256) void convert_weights(
    const float* __restrict__ wq, const float* __restrict__ wk, const float* __restrict__ wv,
    const float* __restrict__ wo, const float* __restrict__ w1, const float* __restrict__ w2,
    u16* __restrict__ owq, u16* __restrict__ owk, u16* __restrict__ owv,
    u16* __restrict__ owo, u16* __restrict__ ow1, u16* __restrict__ ow2) {
  int i = blockIdx.x * 256 + threadIdx.x;  // float4 index, total 614400
  const float* src; u16* dst; int base;
  if (i < 8192)        { src = wq; dst = owq; base = 0; }
  else if (i < 16384)  { src = wk; dst = owk; base = 8192; }
  else if (i < 24576)  { src = wv; dst = owv; base = 16384; }
  else if (i < 90112)  { src = wo; dst = owo; base = 24576; }
  else if (i < 352256) { src = w1; dst = ow1; base = 90112; }
  else                 { src = w2; dst = ow2; base = 352256; }
  int li = i - base;
  float4 v = reinterpret_cast<const float4*>(src)[li];
  ushort4 o;
  o.x = bfbits(v.x); o.y = bfbits(v.y); o.z = bfbits(v.z); o.w = bfbits(v.w);
  reinterpret_cast<ushort4*>(dst)[li] = o;
}

// ---------------- layernorm ----------------
__global__ __launch_bounds__(128) void ln_kernel(const float* __restrict__ x,
    const float* __restrict__ w, const float* __restrict__ b, u16* __restrict__ out) {
  int row = blockIdx.x, tid = threadIdx.x;
  float4 v = reinterpret_cast<const float4*>(x + row * 512)[tid];
  float s  = v.x + v.y + v.z + v.w;
  float s2 = v.x*v.x + v.y*v.y + v.z*v.z + v.w*v.w;
  #pragma unroll
  for (int o = 32; o > 0; o >>= 1) { s += __shfl_down(s, o); s2 += __shfl_down(s2, o); }
  __shared__ float sm[4];
  if ((tid & 63) == 0) { sm[(tid >> 6)*2] = s; sm[(tid >> 6)*2 + 1] = s2; }
  __syncthreads();
  float ts = sm[0] + sm[2], ts2 = sm[1] + sm[3];
  float mean = ts * (1.f/512.f);
  float var  = ts2 * (1.f/512.f) - mean*mean;
  float rstd = rsq_r(var + 1e-5f);
  float4 wv = reinterpret_cast<const float4*>(w)[tid];
  float4 bv = reinterpret_cast<const float4*>(b)[tid];
  ushort4 o;
  o.x = bfbits((v.x-mean)*rstd*wv.x + bv.x);
  o.y = bfbits((v.y-mean)*rstd*wv.y + bv.y);
  o.z = bfbits((v.z-mean)*rstd*wv.z + bv.z);
  o.w = bfbits((v.w-mean)*rstd*wv.w + bv.w);
  reinterpret_cast<ushort4*>(out + row * 512)[tid] = o;
}

// ---------------- QKV projection (q,k,v one pass; also emits per-row norm aux) ----------------
__global__ __launch_bounds__(256) void qkv_kernel(const u16* __restrict__ h1,
    const u16* __restrict__ wqb, const u16* __restrict__ wkb, const u16* __restrict__ wvb,
    u16* __restrict__ q, u16* __restrict__ k, u16* __restrict__ vt,
    float* __restrict__ qsq, float* __restrict__ qom, float* __restrict__ qrs,
    float* __restrict__ ksq, float* __restrict__ kom, float* __restrict__ krs) {
  int mt = blockIdx.x, head = blockIdx.y;
  int wave = threadIdx.x >> 6, lane = threadIdx.x & 63;
  int lr = lane & 15, lg = lane >> 4;
  int m0 = mt * 64 + wave * 16;
  const u16* xr = h1 + (m0 + lr) * 512 + head * 64 + lg * 8;
  bf16x8 a0 = *reinterpret_cast<const bf16x8a*>(xr);
  bf16x8 a1 = *reinterpret_cast<const bf16x8a*>(xr + 32);
  int m_base = m0 + 4*lg;
  int bq = m_base >> 10;
  int s_base = m_base & 1023;
  int bh = (bq << 3) + head;
  #pragma unroll 1
  for (int mat = 0; mat < 3; ++mat) {
    const u16* W = (mat == 0 ? wqb : mat == 1 ? wkb : wvb) + head * 4096;
    f32x4 acc[4];
    #pragma unroll
    for (int c = 0; c < 4; c++)
      #pragma unroll
      for (int j = 0; j < 4; j++) acc[c][j] = 0.f;
    #pragma unroll
    for (int c = 0; c < 4; c++) {
      const u16* wr = W + (c*16 + lr) * 64 + lg * 8;
      bf16x8 b0 = *reinterpret_cast<const bf16x8a*>(wr);
      bf16x8 b1 = *reinterpret_cast<const bf16x8a*>(wr + 32);
      acc[c] = __builtin_amdgcn_mfma_f32_16x16x32_bf16(a0, b0, acc[c], 0, 0, 0);
      acc[c] = __builtin_amdgcn_mfma_f32_16x16x32_bf16(a1, b1, acc[c], 0, 0, 0);
    }
    if (mat == 2) {
      #pragma unroll
      for (int c = 0; c < 4; c++)
        #pragma unroll
        for (int j = 0; j < 4; j++)
          vt[(bh*64 + c*16 + lr) * 1024 + s_base + j] = bfbits(acc[c][j]);
    } else {
      u16* dst = (mat == 0 ? q : k);
      float* sq = (mat == 0 ? qsq : ksq);
      float* om = (mat == 0 ? qom : kom);
      float* rs = (mat == 0 ? qrs : krs);
      float ss[4] = {0.f, 0.f, 0.f, 0.f};
      #pragma unroll
      for (int c = 0; c < 4; c++)
        #pragma unroll
        for (int j = 0; j < 4; j++) {
          float vv = acc[c][j];
          dst[(bh*1024 + s_base + j) * 64 + c*16 + lr] = bfbits(vv);
          ss[j] += vv * vv;
        }
      #pragma unroll
      for (int j = 0; j < 4; j++) {
        #pragma unroll
        for (int o = 1; o < 16; o <<= 1) ss[j] += __shfl_xor(ss[j], o);
      }
      if (lr == 0) {
        #pragma unroll
        for (int j = 0; j < 4; j++) {
          float v = ss[j];
          int idx = bh*1024 + s_base + j;
          sq[idx] = v;
          om[idx] = rcp_r(1.f - v);
          rs[idx] = rsq_r(v);
        }
      }
    }
  }
}

// ---------------- fused product-manifold attention ----------------
// 4 waves/WG (256 thr): one 16-row q-tile, wave = t-split (256 t each).
// 1D grid 2048, XCD-partitioned decode: each XCD owns 4 bh x 64 q-tiles ->
// concurrent K/V working set 1 MB/XCD (fits 4 MB L2). wg->XCD is wg&7 (HW
// round-robin heuristic; perf-only, never correctness).
// Swapped QK^T (q = lane&15); no online max (sim <= 0). PV = mfma(V^T, P^T).
// LDS = 5120B: per-wave P^T staging UNION cross-split f32 reduction slot.
__global__ __launch_bounds__(256, 8) void attn_kernel(
    const u16* __restrict__ q, const u16* __restrict__ k, const u16* __restrict__ vt,
    const float* __restrict__ qsqA, const float* __restrict__ qomA, const float* __restrict__ qrsA,
    const float* __restrict__ ksqA, const float* __restrict__ komA, const float* __restrict__ krsA,
    const float* __restrict__ gw, const float* __restrict__ temp,
    u16* __restrict__ attnb) {
  int wg = blockIdx.x;
  int xcd = wg & 7;
  int slot = wg >> 3;                  // 0..255 per XCD
  int bh = xcd + ((slot >> 6) << 3);   // 4 bh per XCD
  int qt = slot & 63;
  int b = bh >> 3, head = bh & 7;
  int tid = threadIdx.x;
  int wave = tid >> 6;            // t-split 0..3
  int lane = tid & 63;
  int lr = lane & 15, lg = lane >> 4;
  int q0 = qt * 16;

  const u16* qp = q  + bh * 65536;
  const u16* kp = k  + bh * 65536;
  const u16* vp = vt + bh * 65536;
  const float* ksb = ksqA + (bh << 10);
  const float* kob = komA + (bh << 10);
  const float* krb = krsA + (bh << 10);

  __shared__ __align__(16) u16 umem[2560];   // 5120B: plds 4x640 u16 | facc 64x20 f32
  u16* pw = umem + wave * 640;

  float g0 = gw[head*3], g1 = gw[head*3+1], g2 = gw[head*3+2];
  float gm = fmaxf(g0, fmaxf(g1, g2));
  float e0 = __expf(g0-gm), e1 = __expf(g1-gm), e2 = __expf(g2-gm);
  float gi = rcp_r(e0 + e1 + e2);
  float tp = temp[head];
  const float LOG2E = 1.4426950408889634f;
  float chn = -e0*gi*tp;          // hyp stays in log2 domain: exact fold
  float cen = -e1*gi*tp*LOG2E;
  float csn = -e2*gi*tp*LOG2E;

  const u16* qr = qp + (q0 + lr) * 64 + lg * 8;
  bf16x8 aq0 = *reinterpret_cast<const bf16x8a*>(qr);
  bf16x8 aq1 = *reinterpret_cast<const bf16x8a*>(qr + 32);
  float qs  = qsqA[(bh << 10) + q0 + lr];
  float qom = qomA[(bh << 10) + q0 + lr];
  float rqn = qrsA[(bh << 10) + q0 + lr];

  f32x4 acc[4];
  #pragma unroll
  for (int c = 0; c < 4; c++)
    #pragma unroll
    for (int j = 0; j < 4; j++) acc[c][j] = 0.f;
  float psum0 = 0.f, psum1 = 0.f;

  for (int it = 0; it < 8; ++it) {
    int t0 = wave * 256 + it * 32;
    const u16* kr = kp + (t0 + lr) * 64 + lg * 8;
    bf16x8 k00 = *reinterpret_cast<const bf16x8a*>(kr);
    bf16x8 k01 = *reinterpret_cast<const bf16x8a*>(kr + 32);
    bf16x8 k10 = *reinterpret_cast<const bf16x8a*>(kr + 1024);
    bf16x8 k11 = *reinterpret_cast<const bf16x8a*>(kr + 1024 + 32);
    f32x4 s0, s1;
    #pragma unroll
    for (int j = 0; j < 4; j++) { s0[j] = 0.f; s1[j] = 0.f; }
    s0 = __builtin_amdgcn_mfma_f32_16x16x32_bf16(k00, aq0, s0, 0, 0, 0);
    s0 = __builtin_amdgcn_mfma_f32_16x16x32_bf16(k01, aq1, s0, 0, 0, 0);
    s1 = __builtin_amdgcn_mfma_f32_16x16x32_bf16(k10, aq0, s1, 0, 0, 0);
    s1 = __builtin_amdgcn_mfma_f32_16x16x32_bf16(k11, aq1, s1, 0, 0, 0);

    float pv0[4], pv1[4];
    #pragma unroll
    for (int tc = 0; tc < 2; tc++) {
      int tt = t0 + tc*16 + 4*lg;
      f32x4 kq = *reinterpret_cast<const f32x4a*>(ksb + tt);
      f32x4 ko = *reinterpret_cast<const f32x4a*>(kob + tt);
      f32x4 krv = *reinterpret_cast<const f32x4a*>(krb + tt);
      f32x4 sv = tc ? s1 : s0;
      float* pv = tc ? pv1 : pv0;
      #pragma unroll
      for (int j = 0; j < 4; j++) {
        float qk  = sv[j];
        float dsq = fmaxf(fmaf(qk, -2.f, qs + kq[j]), 0.f);
        float euc = sqrt_r(dsq + 1e-8f);
        float u   = (dsq + dsq) * qom * ko[j];
        u = fminf(fmaxf(u, 0.f), 999999.f);      // == clip(cosh_arg,1,1e6)-1
        float hyp2 = log2_r((u + 1.f) + sqrt_r(u * (u + 2.f)));  // acosh * log2e
        float ca = qk * rqn * krv[j];
        ca = fminf(fmaxf(ca, -1.f), 1.f);
        float aa = fabsf(ca);
        float pp = fmaf(aa, -0.0187293f, 0.0742610f);
        pp = fmaf(aa, pp, -0.2121144f);
        pp = fmaf(aa, pp, 1.5707288f);
        float rr = sqrt_r(1.f - aa) * pp;
        float sph = ca < 0.f ? 3.14159265358979f - rr : rr;
        float sim2 = fmaf(chn, hyp2, fmaf(cen, euc, csn * sph));
        float p = exp2_r(sim2);
        if (tc) psum1 += p; else psum0 += p;
        pv[j] = p;
      }
    }
    u32 w0 = cvt_pk_bf16(pv0[0], pv0[1]);
    u32 w1 = cvt_pk_bf16(pv0[2], pv0[3]);
    u32 w2 = cvt_pk_bf16(pv1[0], pv1[1]);
    u32 w3 = cvt_pk_bf16(pv1[2], pv1[3]);
    *reinterpret_cast<uint2a*>(pw + lr*40 + 4*lg)      = make_uint2(w0, w1);
    *reinterpret_cast<uint2a*>(pw + lr*40 + 16 + 4*lg) = make_uint2(w2, w3);
    bf16x8 pa = *reinterpret_cast<const bf16x8a*>(pw + lr*40 + lg*8);
    #pragma unroll
    for (int c = 0; c < 4; c++) {
      bf16x8 av = *reinterpret_cast<const bf16x8a*>(vp + (c*16 + lr)*1024 + t0 + lg*8);
      acc[c] = __builtin_amdgcn_mfma_f32_16x16x32_bf16(av, pa, acc[c], 0, 0, 0);
    }
  }

  float lt = psum0 + psum1;
  lt += __shfl_xor(lt, 16);
  lt += __shfl_xor(lt, 32);

  // sequential cross-split reduction through one 5120B slot (union with plds)
  float* fa = (float*)umem;
  __syncthreads();                                       // plds dead
  #pragma unroll 1
  for (int s = 1; s <= 3; ++s) {
    if (wave == s) {
      #pragma unroll
      for (int c = 0; c < 4; c++)
        *reinterpret_cast<f32x4a*>(fa + lane*20 + c*4) = acc[c];
      fa[lane*20 + 16] = lt;
    }
    __syncthreads();
    if (wave == 0) {
      #pragma unroll
      for (int c = 0; c < 4; c++)
        acc[c] += *reinterpret_cast<const f32x4a*>(fa + lane*20 + c*4);
      lt += fa[lane*20 + 16];
    }
    __syncthreads();
  }
  if (wave == 0) {
    float rl = rcp_r(lt);
    #pragma unroll
    for (int c = 0; c < 4; c++) {
      ushort4 st;
      st.x = bfbits(acc[c][0]*rl); st.y = bfbits(acc[c][1]*rl);
      st.z = bfbits(acc[c][2]*rl); st.w = bfbits(acc[c][3]*rl);
      *reinterpret_cast<ushort4*>(
          &attnb[(size_t)((b << 10) + q0 + lr) * 512 + head*64 + c*16 + 4*lg]) = st;
    }
  }
}

// ---------------- tiled GEMM  Y = epilogue(X @ W^T + bias) ----------------
// BM=64, BK=32, 4 waves 2x2, global_load_lds(16B), XOR slot-swizzle both sides.
// MODE 0: outf=acc+bias+res  MODE 1: outb=bf16(gelu)  MODE 3: f32 partial (split-K via blockIdx.z)
template<int K, int KS, int BN, int MODE>
__global__ __launch_bounds__(256, 4) void gemm_kernel(
    const u16* __restrict__ X, const u16* __restrict__ W,
    const float* __restrict__ bias, const float* __restrict__ res,
    float* __restrict__ outf, float* __restrict__ outf2, u16* __restrict__ outb,
    const float* __restrict__ gw, float* __restrict__ wout) {
  constexpr int NS = (MODE == 1) ? 2048 : 512;
  constexpr int WN = BN / 2;
  constexpr int NFC = WN / 16;
  __shared__ u16 As[64 * 32];
  __shared__ u16 Bs[BN * 32];
  int tid = threadIdx.x;
  int wave = tid >> 6, lane = tid & 63;
  int lr = lane & 15, lg = lane >> 4;
  int wr = wave >> 1, wc = wave & 1;
  int m0 = blockIdx.x * 64, n0 = blockIdx.y * BN;
  const u16* Xp = X;
  const u16* Wp = W;
  if constexpr (MODE == 3) { Xp += blockIdx.z * (KS/2); Wp += blockIdx.z * (KS/2); }
  f32x4 acc[2][NFC];
  #pragma unroll
  for (int fr = 0; fr < 2; fr++)
    #pragma unroll
    for (int fc = 0; fc < NFC; fc++)
      #pragma unroll
      for (int j = 0; j < 4; j++) acc[fr][fc][j] = 0.f;
  // staging: chunk c -> row c>>2, 16B slot c&3; source col inverse-swizzled
  int arow = tid >> 2;
  int acol = ((tid & 3) ^ (arow & 3)) << 3;
  const u16* Ag = Xp + (size_t)(m0 + arow) * KS + acol;
  u16* Al = As + wave * 512;
  const u16* Bg0 = Wp + (size_t)(n0 + arow) * KS + acol;
  u16* Bl0 = Bs + wave * 512;
  const u16* Bg1 = nullptr; u16* Bl1 = nullptr;
  if constexpr (BN == 128) {
    int c1 = 256 + tid, r1 = c1 >> 2;
    int s1 = ((c1 & 3) ^ (r1 & 3)) << 3;
    Bg1 = Wp + (size_t)(n0 + r1) * KS + s1;
    Bl1 = Bs + 2048 + wave * 512;
  }
  int rdcol = ((lg ^ (lr & 3)) << 3);
  for (int k0 = 0; k0 < K; k0 += 32) {
    __syncthreads();
    gload_lds16(Ag + k0, Al);
    if (BN != 32 || tid < 128) gload_lds16(Bg0 + k0, Bl0);
    if constexpr (BN == 128) gload_lds16(Bg1 + k0, Bl1);
    __syncthreads();
    bf16x8 af[2], bfr[NFC];
    #pragma unroll
    for (int fr = 0; fr < 2; fr++)
      af[fr] = *reinterpret_cast<const bf16x8a*>(As + (wr*32 + fr*16 + lr)*32 + rdcol);
    #pragma unroll
    for (int fc = 0; fc < NFC; fc++)
      bfr[fc] = *reinterpret_cast<const bf16x8a*>(Bs + (wc*WN + fc*16 + lr)*32 + rdcol);
    #pragma unroll
    for (int fr = 0; fr < 2; fr++)
      #pragma unroll
      for (int fc = 0; fc < NFC; fc++)
        acc[fr][fc] = __builtin_amdgcn_mfma_f32_16x16x32_bf16(af[fr], bfr[fc], acc[fr][fc], 0, 0, 0);
  }
  float* po = nullptr;
  if constexpr (MODE == 3) po = blockIdx.z ? outf2 : outf;
  #pragma unroll
  for (int fr = 0; fr < 2; fr++)
    #pragma unroll
    for (int fc = 0; fc < NFC; fc++) {
      int col = n0 + wc*WN + fc*16 + lr;
      float bb = (MODE == 3) ? 0.f : bias[col];
      #pragma unroll
      for (int j = 0; j < 4; j++) {
        int row = m0 + wr*32 + fr*16 + 4*lg + j;
        float v = acc[fr][fc][j] + bb;
        if constexpr (MODE == 0) {
          outf[(size_t)row*NS + col] = v + res[(size_t)row*NS + col];
        } else if constexpr (MODE == 1) {
          float t = v * fmaf(v*v, 0.035677408137f, 0.7978845608f);
          float g = v * rcp_r(1.f + exp2_r(-2.8853900817779268f * t));
          outb[(size_t)row*NS + col] = bfbits(g);
        } else {
          po[(size_t)row*512 + col] = v;
        }
      }
    }
  (void)gw; (void)wout;
}

// ---------------- FF2 split-K combine: out = p0 + p1 + bias + res (+ gw softmax) ---------
__global__ __launch_bounds__(256) void ff2_combine(
    const float* __restrict__ p0, const float* __restrict__ p1,
    const float* __restrict__ bias, const float* __restrict__ res,
    float* __restrict__ out, const float* __restrict__ gw, float* __restrict__ wout) {
  int i = blockIdx.x * 256 + threadIdx.x;   // float4 index, total 524288
  float4 a = reinterpret_cast<const float4*>(p0)[i];
  float4 b = reinterpret_cast<const float4*>(p1)[i];
  float4 r = reinterpret_cast<const float4*>(res)[i];
  int col4 = (i & 127) << 2;
  float4 bb = *reinterpret_cast<const float4*>(bias + col4);
  float4 o;
  o.x = a.x + b.x + r.x + bb.x;
  o.y = a.y + b.y + r.y + bb.y;
  o.z = a.z + b.z + r.z + bb.z;
  o.w = a.w + b.w + r.w + bb.w;
  reinterpret_cast<float4*>(out)[i] = o;
  if (blockIdx.x == 0 && threadIdx.x < 8) {
    int h = threadIdx.x;
    float a0 = gw[h*3], a1 = gw[h*3+1], a2 = gw[h*3+2];
    float m = fmaxf(a0, fmaxf(a1, a2));
    float x0 = __expf(a0-m), x1 = __expf(a1-m), x2 = __expf(a2-m);
    float inv = rcp_r(x0 + x1 + x2);
    wout[h*3+0] = x0*inv; wout[h*3+1] = x1*inv; wout[h*3+2] = x2*inv;
  }
}

extern "C" void kernel_launch(void* const* d_in, const int* in_sizes, int n_in,
                              void* d_out, int out_size, void* d_ws, size_t ws_size,
                              hipStream_t stream) {
  const float* x    = (const float*)d_in[0];
  const float* Wq   = (const float*)d_in[1];
  const float* Wk   = (const float*)d_in[2];
  const float* Wv   = (const float*)d_in[3];
  const float* gw   = (const float*)d_in[4];
  const float* temp = (const float*)d_in[5];
  const float* Wo   = (const float*)d_in[6];
  const float* bo   = (const float*)d_in[7];
  const float* ln1w = (const float*)d_in[8];
  const float* ln1b = (const float*)d_in[9];
  const float* ln2w = (const float*)d_in[10];
  const float* ln2b = (const float*)d_in[11];
  const float* W1   = (const float*)d_in[12];
  const float* b1   = (const float*)d_in[13];
  const float* W2   = (const float*)d_in[14];
  const float* b2   = (const float*)d_in[15];

  char* ws = (char*)d_ws;
  u16*  wqb  = (u16*)(ws + 0);
  u16*  wkb  = (u16*)(ws + 65536);
  u16*  wvb  = (u16*)(ws + 131072);
  u16*  wob  = (u16*)(ws + 196608);
  u16*  w1b  = (u16*)(ws + 720896);
  u16*  w2b  = (u16*)(ws + 2818048);
  u16*  h1b  = (u16*)(ws + 4915200);
  u16*  qb   = (u16*)(ws + 9109504);
  u16*  kb   = (u16*)(ws + 13303808);
  u16*  vtb  = (u16*)(ws + 17498112);
  float* qsq = (float*)(ws + 21692416);
  float* ksq = (float*)(ws + 21823488);
  float* qom = (float*)(ws + 21954560);
  float* qrs = (float*)(ws + 22085632);
  float* kom = (float*)(ws + 22216704);
  float* krs = (float*)(ws + 22347776);
  u16*  attnb= (u16*)(ws + 22478848);
  float* x1  = (float*)(ws + 26673152);
  u16*  h2b  = (u16*)(ws + 35061760);
  float* p1f = (float*)(ws + 35061760);  // aliases h2b (dead after FF1) + 4.2MB beyond
  u16*  gb   = (u16*)(ws + 4915200);     // aliases h1b/qb/kb/vtb (dead before FF1)

  float* outf = (float*)d_out;
  float* wout = outf + 4096*512;

  convert_weights<<<2400, 256, 0, stream>>>(Wq, Wk, Wv, Wo, W1, W2,
                                            wqb, wkb, wvb, wob, w1b, w2b);
  ln_kernel<<<4096, 128, 0, stream>>>(x, ln1w, ln1b, h1b);
  qkv_kernel<<<dim3(64, 8), 256, 0, stream>>>(h1b, wqb, wkb, wvb, qb, kb, vtb,
                                              qsq, qom, qrs, ksq, kom, krs);
  attn_kernel<<<2048, 256, 0, stream>>>(qb, kb, vtb, qsq, qom, qrs,
                                        ksq, kom, krs, gw, temp, attnb);
  gemm_kernel<512, 512, 64, 0><<<dim3(64, 8), 256, 0, stream>>>(
      attnb, wob, bo, x, x1, nullptr, nullptr, nullptr, nullptr);
  ln_kernel<<<4096, 128, 0, stream>>>(x1, ln2w, ln2b, h2b);
  gemm_kernel<512, 512, 128, 1><<<dim3(64, 16), 256, 0, stream>>>(
      h2b, w1b, b1, nullptr, nullptr, nullptr, gb, nullptr, nullptr);
  gemm_kernel<1024, 2048, 64, 3><<<dim3(64, 8, 2), 256, 0, stream>>>(
      gb, w2b, nullptr, nullptr, outf, p1f, nullptr, nullptr, nullptr);
  ff2_combine<<<2048, 256, 0, stream>>>(outf, p1f, b2, x1, outf, gw, wout);
}

// Round 8
// 222.877 us; speedup vs baseline: 1.1888x; 1.1888x over previous
//
#include <hip/hip_runtime.h>
#include <hip/hip_bf16.h>
#include <math.h>

typedef __attribute__((ext_vector_type(4))) float f32x4;
typedef __attribute__((ext_vector_type(8))) short bf16x8;
typedef unsigned short u16;
typedef unsigned int u32;

typedef f32x4  __attribute__((may_alias)) f32x4a;
typedef bf16x8 __attribute__((may_alias)) bf16x8a;
typedef uint2  __attribute__((may_alias)) uint2a;

__device__ __forceinline__ u16 bfbits(float f) {
  union { __hip_bfloat16 h; u16 u; } cv;
  cv.h = __float2bfloat16(f);
  return cv.u;
}
__device__ __forceinline__ float rcp_r(float x)  { return __builtin_amdgcn_rcpf(x); }
__device__ __forceinline__ float sqrt_r(float x) { return __builtin_amdgcn_sqrtf(x); }
__device__ __forceinline__ float log2_r(float x) { return __builtin_amdgcn_logf(x); }
__device__ __forceinline__ float exp2_r(float x) { return __builtin_amdgcn_exp2f(x); }
__device__ __forceinline__ float rsq_r(float x)  { return __builtin_amdgcn_rsqf(x); }
__device__ __forceinline__ u32 cvt_pk_bf16(float lo, float hi) {
  u32 r;
  asm("v_cvt_pk_bf16_f32 %0, %1, %2" : "=v"(r) : "v"(lo), "v"(hi));
  return r;
}
typedef const __attribute__((address_space(1))) unsigned int* gas_t;
typedef __attribute__((address_space(3))) unsigned int* las_t;
__device__ __forceinline__ void gload_lds16(const u16* g, u16* l) {
  __builtin_amdgcn_global_load_lds((gas_t)g, (las_t)l, 16, 0, 0);
}

// ---------------- weight fp32 -> bf16 ----------------
__global__ __launch_bounds__(256) void convert_weights(
    const float* __restrict__ wq, const float* __restrict__ wk, const float* __restrict__ wv,
    const float* __restrict__ wo, const float* __restrict__ w1, const float* __restrict__ w2,
    u16* __restrict__ owq, u16* __restrict__ owk, u16* __restrict__ owv,
    u16* __restrict__ owo, u16* __restrict__ ow1, u16* __restrict__ ow2) {
  int i = blockIdx.x * 256 + threadIdx.x;  // float4 index, total 614400
  const float* src; u16* dst; int base;
  if (i < 8192)        { src = wq; dst = owq; base = 0; }
  else if (i < 16384)  { src = wk; dst = owk; base = 8192; }
  else if (i < 24576)  { src = wv; dst = owv; base = 16384; }
  else if (i < 90112)  { src = wo; dst = owo; base = 24576; }
  else if (i < 352256) { src = w1; dst = ow1; base = 90112; }
  else                 { src = w2; dst = ow2; base = 352256; }
  int li = i - base;
  float4 v = reinterpret_cast<const float4*>(src)[li];
  ushort4 o;
  o.x = bfbits(v.x); o.y = bfbits(v.y); o.z = bfbits(v.z); o.w = bfbits(v.w);
  reinterpret_cast<ushort4*>(dst)[li] = o;
}

// ---------------- layernorm ----------------
__global__ __launch_bounds__(128) void ln_kernel(const float* __restrict__ x,
    const float* __restrict__ w, const float* __restrict__ b, u16* __restrict__ out) {
  int row = blockIdx.x, tid = threadIdx.x;
  float4 v = reinterpret_cast<const float4*>(x + row * 512)[tid];
  float s  = v.x + v.y + v.z + v.w;
  float s2 = v.x*v.x + v.y*v.y + v.z*v.z + v.w*v.w;
  #pragma unroll
  for (int o = 32; o > 0; o >>= 1) { s += __shfl_down(s, o); s2 += __shfl_down(s2, o); }
  __shared__ float sm[4];
  if ((tid & 63) == 0) { sm[(tid >> 6)*2] = s; sm[(tid >> 6)*2 + 1] = s2; }
  __syncthreads();
  float ts = sm[0] + sm[2], ts2 = sm[1] + sm[3];
  float mean = ts * (1.f/512.f);
  float var  = ts2 * (1.f/512.f) - mean*mean;
  float rstd = rsq_r(var + 1e-5f);
  float4 wv = reinterpret_cast<const float4*>(w)[tid];
  float4 bv = reinterpret_cast<const float4*>(b)[tid];
  ushort4 o;
  o.x = bfbits((v.x-mean)*rstd*wv.x + bv.x);
  o.y = bfbits((v.y-mean)*rstd*wv.y + bv.y);
  o.z = bfbits((v.z-mean)*rstd*wv.z + bv.z);
  o.w = bfbits((v.w-mean)*rstd*wv.w + bv.w);
  reinterpret_cast<ushort4*>(out + row * 512)[tid] = o;
}

// ---------------- QKV projection (q,k,v one pass; also emits per-row norm aux) ----------------
__global__ __launch_bounds__(256) void qkv_kernel(const u16* __restrict__ h1,
    const u16* __restrict__ wqb, const u16* __restrict__ wkb, const u16* __restrict__ wvb,
    u16* __restrict__ q, u16* __restrict__ k, u16* __restrict__ vt,
    float* __restrict__ qsq, float* __restrict__ qrs,
    float* __restrict__ ksq, float* __restrict__ krs) {
  int mt = blockIdx.x, head = blockIdx.y;
  int wave = threadIdx.x >> 6, lane = threadIdx.x & 63;
  int lr = lane & 15, lg = lane >> 4;
  int m0 = mt * 64 + wave * 16;
  const u16* xr = h1 + (m0 + lr) * 512 + head * 64 + lg * 8;
  bf16x8 a0 = *reinterpret_cast<const bf16x8a*>(xr);
  bf16x8 a1 = *reinterpret_cast<const bf16x8a*>(xr + 32);
  int m_base = m0 + 4*lg;
  int bq = m_base >> 10;
  int s_base = m_base & 1023;
  int bh = (bq << 3) + head;
  #pragma unroll 1
  for (int mat = 0; mat < 3; ++mat) {
    const u16* W = (mat == 0 ? wqb : mat == 1 ? wkb : wvb) + head * 4096;
    f32x4 acc[4];
    #pragma unroll
    for (int c = 0; c < 4; c++)
      #pragma unroll
      for (int j = 0; j < 4; j++) acc[c][j] = 0.f;
    #pragma unroll
    for (int c = 0; c < 4; c++) {
      const u16* wr = W + (c*16 + lr) * 64 + lg * 8;
      bf16x8 b0 = *reinterpret_cast<const bf16x8a*>(wr);
      bf16x8 b1 = *reinterpret_cast<const bf16x8a*>(wr + 32);
      acc[c] = __builtin_amdgcn_mfma_f32_16x16x32_bf16(a0, b0, acc[c], 0, 0, 0);
      acc[c] = __builtin_amdgcn_mfma_f32_16x16x32_bf16(a1, b1, acc[c], 0, 0, 0);
    }
    if (mat == 2) {
      #pragma unroll
      for (int c = 0; c < 4; c++)
        #pragma unroll
        for (int j = 0; j < 4; j++)
          vt[(bh*64 + c*16 + lr) * 1024 + s_base + j] = bfbits(acc[c][j]);
    } else {
      u16* dst = (mat == 0 ? q : k);
      float* sq = (mat == 0 ? qsq : ksq);
      float* rs = (mat == 0 ? qrs : krs);
      float ss[4] = {0.f, 0.f, 0.f, 0.f};
      #pragma unroll
      for (int c = 0; c < 4; c++)
        #pragma unroll
        for (int j = 0; j < 4; j++) {
          float vv = acc[c][j];
          dst[(bh*1024 + s_base + j) * 64 + c*16 + lr] = bfbits(vv);
          ss[j] += vv * vv;
        }
      #pragma unroll
      for (int j = 0; j < 4; j++) {
        #pragma unroll
        for (int o = 1; o < 16; o <<= 1) ss[j] += __shfl_xor(ss[j], o);
      }
      if (lr == 0) {
        #pragma unroll
        for (int j = 0; j < 4; j++) {
          float v = ss[j];
          int idx = bh*1024 + s_base + j;
          sq[idx] = v;
          rs[idx] = rsq_r(v);
        }
      }
    }
  }
}

// ---------------- fused product-manifold attention ----------------
// R3 structure (proven 70us): 8 waves/WG, 2 q-subtiles x 4 t-splits, grid (32,32),
// k-aux (ksq, 1/|k|) preloaded in LDS. ONLY change vs R3: sequential 3-phase
// cross-split reduction through a 10240B slot unioned with P-staging ->
// LDS 40448 -> 18432 B -> 3 WG/CU (24 waves) instead of 1.58 (12.6 waves).
// Swapped QK^T (q = lane&15); no online max (sim <= 0). PV = mfma(V^T, P^T).
__global__ __launch_bounds__(512, 6) void attn_kernel(
    const u16* __restrict__ q, const u16* __restrict__ k, const u16* __restrict__ vt,
    const float* __restrict__ qsqA, const float* __restrict__ qrsA,
    const float* __restrict__ ksqA, const float* __restrict__ krsA,
    const float* __restrict__ gw, const float* __restrict__ temp,
    u16* __restrict__ attnb) {
  int bh = blockIdx.y;
  int b = bh >> 3, head = bh & 7;
  int tid = threadIdx.x;
  int wave = tid >> 6;
  int wq = wave & 1;       // q sub-tile
  int split = wave >> 1;   // t-split 0..3
  int lane = tid & 63;
  int lr = lane & 15, lg = lane >> 4;
  int q0 = blockIdx.x * 32 + wq * 16;

  const u16* qp = q  + bh * 65536;
  const u16* kp = k  + bh * 65536;
  const u16* vp = vt + bh * 65536;

  __shared__ float ks_s[1024], rkn_s[1024];
  __shared__ __align__(16) u16 umem[5120];   // 10240B: plds 8x640 u16 | 128x20 f32 red. slot
  u16* pw = umem + wave * 640;

  for (int i = tid; i < 1024; i += 512) {
    ks_s[i]  = ksqA[(bh << 10) + i];
    rkn_s[i] = krsA[(bh << 10) + i];
  }
  __syncthreads();

  float g0 = gw[head*3], g1 = gw[head*3+1], g2 = gw[head*3+2];
  float gm = fmaxf(g0, fmaxf(g1, g2));
  float e0 = __expf(g0-gm), e1 = __expf(g1-gm), e2 = __expf(g2-gm);
  float gi = rcp_r(e0 + e1 + e2);
  float tp = temp[head];
  const float LOG2E = 1.4426950408889634f;
  float chn = -e0*gi*tp;          // hyp stays in log2 domain: exact fold
  float cen = -e1*gi*tp*LOG2E;
  float csn = -e2*gi*tp*LOG2E;

  const u16* qr = qp + (q0 + lr) * 64 + lg * 8;
  bf16x8 aq0 = *reinterpret_cast<const bf16x8a*>(qr);
  bf16x8 aq1 = *reinterpret_cast<const bf16x8a*>(qr + 32);
  float qs  = qsqA[(bh << 10) + q0 + lr];
  float omq = 1.f - qs;
  float rqn = qrsA[(bh << 10) + q0 + lr];

  f32x4 acc[4];
  #pragma unroll
  for (int c = 0; c < 4; c++)
    #pragma unroll
    for (int j = 0; j < 4; j++) acc[c][j] = 0.f;
  float psum0 = 0.f, psum1 = 0.f;

  for (int it = 0; it < 8; ++it) {
    int t0 = split * 256 + it * 32;
    const u16* kr = kp + (t0 + lr) * 64 + lg * 8;
    bf16x8 k00 = *reinterpret_cast<const bf16x8a*>(kr);
    bf16x8 k01 = *reinterpret_cast<const bf16x8a*>(kr + 32);
    bf16x8 k10 = *reinterpret_cast<const bf16x8a*>(kr + 1024);
    bf16x8 k11 = *reinterpret_cast<const bf16x8a*>(kr + 1024 + 32);
    f32x4 s0, s1;
    #pragma unroll
    for (int j = 0; j < 4; j++) { s0[j] = 0.f; s1[j] = 0.f; }
    s0 = __builtin_amdgcn_mfma_f32_16x16x32_bf16(k00, aq0, s0, 0, 0, 0);
    s0 = __builtin_amdgcn_mfma_f32_16x16x32_bf16(k01, aq1, s0, 0, 0, 0);
    s1 = __builtin_amdgcn_mfma_f32_16x16x32_bf16(k10, aq0, s1, 0, 0, 0);
    s1 = __builtin_amdgcn_mfma_f32_16x16x32_bf16(k11, aq1, s1, 0, 0, 0);

    f32x4 kq0 = *reinterpret_cast<const f32x4a*>(&ks_s[t0 + 4*lg]);
    f32x4 kq1 = *reinterpret_cast<const f32x4a*>(&ks_s[t0 + 16 + 4*lg]);
    f32x4 rk0 = *reinterpret_cast<const f32x4a*>(&rkn_s[t0 + 4*lg]);
    f32x4 rk1 = *reinterpret_cast<const f32x4a*>(&rkn_s[t0 + 16 + 4*lg]);

    float pv0[4], pv1[4];
    #pragma unroll
    for (int tc = 0; tc < 2; tc++) {
      f32x4 sv = tc ? s1 : s0;
      f32x4 kq = tc ? kq1 : kq0;
      f32x4 rk = tc ? rk1 : rk0;
      float* pv = tc ? pv1 : pv0;
      #pragma unroll
      for (int j = 0; j < 4; j++) {
        float qk  = sv[j];
        float ksj = kq[j];
        float dsq = fmaxf(fmaf(qk, -2.f, qs + ksj), 0.f);
        float euc = sqrt_r(dsq + 1e-8f);
        float den = fmaf(omq, 1.f - ksj, 1e-8f);
        float u   = (dsq + dsq) * rcp_r(den);
        u = fminf(fmaxf(u, 0.f), 999999.f);      // == clip(cosh_arg,1,1e6)-1
        float hyp2 = log2_r((u + 1.f) + sqrt_r(u * (u + 2.f)));  // acosh * log2e
        float ca = qk * rqn * rk[j];
        ca = fminf(fmaxf(ca, -1.f), 1.f);
        float aa = fabsf(ca);
        float pp = fmaf(aa, -0.0187293f, 0.0742610f);
        pp = fmaf(aa, pp, -0.2121144f);
        pp = fmaf(aa, pp, 1.5707288f);
        float rr = sqrt_r(1.f - aa) * pp;
        float sph = ca < 0.f ? 3.14159265358979f - rr : rr;
        float sim2 = fmaf(chn, hyp2, fmaf(cen, euc, csn * sph));
        float p = exp2_r(sim2);
        if (tc) psum1 += p; else psum0 += p;
        pv[j] = p;
      }
    }
    u32 w0 = cvt_pk_bf16(pv0[0], pv0[1]);
    u32 w1 = cvt_pk_bf16(pv0[2], pv0[3]);
    u32 w2 = cvt_pk_bf16(pv1[0], pv1[1]);
    u32 w3 = cvt_pk_bf16(pv1[2], pv1[3]);
    *reinterpret_cast<uint2a*>(pw + lr*40 + 4*lg)      = make_uint2(w0, w1);
    *reinterpret_cast<uint2a*>(pw + lr*40 + 16 + 4*lg) = make_uint2(w2, w3);
    bf16x8 pa = *reinterpret_cast<const bf16x8a*>(pw + lr*40 + lg*8);
    #pragma unroll
    for (int c = 0; c < 4; c++) {
      bf16x8 av = *reinterpret_cast<const bf16x8a*>(vp + (c*16 + lr)*1024 + t0 + lg*8);
      acc[c] = __builtin_amdgcn_mfma_f32_16x16x32_bf16(av, pa, acc[c], 0, 0, 0);
    }
  }

  float lt = psum0 + psum1;
  lt += __shfl_xor(lt, 16);
  lt += __shfl_xor(lt, 32);

  // sequential cross-split reduction through the 10240B union slot
  float* fa = (float*)umem;
  __syncthreads();                                       // plds dead
  #pragma unroll 1
  for (int s = 1; s <= 3; ++s) {
    int base = (wq*64 + lane)*20;
    if (split == s) {
      #pragma unroll
      for (int c = 0; c < 4; c++)
        *reinterpret_cast<f32x4a*>(fa + base + c*4) = acc[c];
      fa[base + 16] = lt;
    }
    __syncthreads();
    if (split == 0) {
      #pragma unroll
      for (int c = 0; c < 4; c++)
        acc[c] += *reinterpret_cast<const f32x4a*>(fa + base + c*4);
      lt += fa[base + 16];
    }
    __syncthreads();
  }
  if (split == 0) {
    float rl = rcp_r(lt);
    #pragma unroll
    for (int c = 0; c < 4; c++) {
      ushort4 st;
      st.x = bfbits(acc[c][0]*rl); st.y = bfbits(acc[c][1]*rl);
      st.z = bfbits(acc[c][2]*rl); st.w = bfbits(acc[c][3]*rl);
      *reinterpret_cast<ushort4*>(
          &attnb[(size_t)((b << 10) + q0 + lr) * 512 + head*64 + c*16 + 4*lg]) = st;
    }
  }
}

// ---------------- tiled GEMM  Y = epilogue(X @ W^T + bias) ----------------
// BM=64, BK=32, 4 waves 2x2, global_load_lds(16B), XOR slot-swizzle both sides.
// MODE 0: outf=acc+bias+res  MODE 1: outb=bf16(gelu)  MODE 3: f32 partial (split-K via blockIdx.z)
template<int K, int KS, int BN, int MODE>
__global__ __launch_bounds__(256, 4) void gemm_kernel(
    const u16* __restrict__ X, const u16* __restrict__ W,
    const float* __restrict__ bias, const float* __restrict__ res,
    float* __restrict__ outf, float* __restrict__ outf2, u16* __restrict__ outb,
    const float* __restrict__ gw, float* __restrict__ wout) {
  constexpr int NS = (MODE == 1) ? 2048 : 512;
  constexpr int WN = BN / 2;
  constexpr int NFC = WN / 16;
  __shared__ u16 As[64 * 32];
  __shared__ u16 Bs[BN * 32];
  int tid = threadIdx.x;
  int wave = tid >> 6, lane = tid & 63;
  int lr = lane & 15, lg = lane >> 4;
  int wr = wave >> 1, wc = wave & 1;
  int m0 = blockIdx.x * 64, n0 = blockIdx.y * BN;
  const u16* Xp = X;
  const u16* Wp = W;
  if constexpr (MODE == 3) { Xp += blockIdx.z * (KS/2); Wp += blockIdx.z * (KS/2); }
  f32x4 acc[2][NFC];
  #pragma unroll
  for (int fr = 0; fr < 2; fr++)
    #pragma unroll
    for (int fc = 0; fc < NFC; fc++)
      #pragma unroll
      for (int j = 0; j < 4; j++) acc[fr][fc][j] = 0.f;
  // staging: chunk c -> row c>>2, 16B slot c&3; source col inverse-swizzled
  int arow = tid >> 2;
  int acol = ((tid & 3) ^ (arow & 3)) << 3;
  const u16* Ag = Xp + (size_t)(m0 + arow) * KS + acol;
  u16* Al = As + wave * 512;
  const u16* Bg0 = Wp + (size_t)(n0 + arow) * KS + acol;
  u16* Bl0 = Bs + wave * 512;
  const u16* Bg1 = nullptr; u16* Bl1 = nullptr;
  if constexpr (BN == 128) {
    int c1 = 256 + tid, r1 = c1 >> 2;
    int s1 = ((c1 & 3) ^ (r1 & 3)) << 3;
    Bg1 = Wp + (size_t)(n0 + r1) * KS + s1;
    Bl1 = Bs + 2048 + wave * 512;
  }
  int rdcol = ((lg ^ (lr & 3)) << 3);
  for (int k0 = 0; k0 < K; k0 += 32) {
    __syncthreads();
    gload_lds16(Ag + k0, Al);
    if (BN != 32 || tid < 128) gload_lds16(Bg0 + k0, Bl0);
    if constexpr (BN == 128) gload_lds16(Bg1 + k0, Bl1);
    __syncthreads();
    bf16x8 af[2], bfr[NFC];
    #pragma unroll
    for (int fr = 0; fr < 2; fr++)
      af[fr] = *reinterpret_cast<const bf16x8a*>(As + (wr*32 + fr*16 + lr)*32 + rdcol);
    #pragma unroll
    for (int fc = 0; fc < NFC; fc++)
      bfr[fc] = *reinterpret_cast<const bf16x8a*>(Bs + (wc*WN + fc*16 + lr)*32 + rdcol);
    #pragma unroll
    for (int fr = 0; fr < 2; fr++)
      #pragma unroll
      for (int fc = 0; fc < NFC; fc++)
        acc[fr][fc] = __builtin_amdgcn_mfma_f32_16x16x32_bf16(af[fr], bfr[fc], acc[fr][fc], 0, 0, 0);
  }
  float* po = nullptr;
  if constexpr (MODE == 3) po = blockIdx.z ? outf2 : outf;
  #pragma unroll
  for (int fr = 0; fr < 2; fr++)
    #pragma unroll
    for (int fc = 0; fc < NFC; fc++) {
      int col = n0 + wc*WN + fc*16 + lr;
      float bb = (MODE == 3) ? 0.f : bias[col];
      #pragma unroll
      for (int j = 0; j < 4; j++) {
        int row = m0 + wr*32 + fr*16 + 4*lg + j;
        float v = acc[fr][fc][j] + bb;
        if constexpr (MODE == 0) {
          outf[(size_t)row*NS + col] = v + res[(size_t)row*NS + col];
        } else if constexpr (MODE == 1) {
          float t = v * fmaf(v*v, 0.035677408137f, 0.7978845608f);
          float g = v * rcp_r(1.f + exp2_r(-2.8853900817779268f * t));
          outb[(size_t)row*NS + col] = bfbits(g);
        } else {
          po[(size_t)row*512 + col] = v;
        }
      }
    }
  (void)gw; (void)wout;
}

// ---------------- FF2 split-K combine: out = p0 + p1 + bias + res (+ gw softmax) ---------
__global__ __launch_bounds__(256) void ff2_combine(
    const float* __restrict__ p0, const float* __restrict__ p1,
    const float* __restrict__ bias, const float* __restrict__ res,
    float* __restrict__ out, const float* __restrict__ gw, float* __restrict__ wout) {
  int i = blockIdx.x * 256 + threadIdx.x;   // float4 index, total 524288
  float4 a = reinterpret_cast<const float4*>(p0)[i];
  float4 b = reinterpret_cast<const float4*>(p1)[i];
  float4 r = reinterpret_cast<const float4*>(res)[i];
  int col4 = (i & 127) << 2;
  float4 bb = *reinterpret_cast<const float4*>(bias + col4);
  float4 o;
  o.x = a.x + b.x + r.x + bb.x;
  o.y = a.y + b.y + r.y + bb.y;
  o.z = a.z + b.z + r.z + bb.z;
  o.w = a.w + b.w + r.w + bb.w;
  reinterpret_cast<float4*>(out)[i] = o;
  if (blockIdx.x == 0 && threadIdx.x < 8) {
    int h = threadIdx.x;
    float a0 = gw[h*3], a1 = gw[h*3+1], a2 = gw[h*3+2];
    float m = fmaxf(a0, fmaxf(a1, a2));
    float x0 = __expf(a0-m), x1 = __expf(a1-m), x2 = __expf(a2-m);
    float inv = rcp_r(x0 + x1 + x2);
    wout[h*3+0] = x0*inv; wout[h*3+1] = x1*inv; wout[h*3+2] = x2*inv;
  }
}

extern "C" void kernel_launch(void* const* d_in, const int* in_sizes, int n_in,
                              void* d_out, int out_size, void* d_ws, size_t ws_size,
                              hipStream_t stream) {
  const float* x    = (const float*)d_in[0];
  const float* Wq   = (const float*)d_in[1];
  const float* Wk   = (const float*)d_in[2];
  const float* Wv   = (const float*)d_in[3];
  const float* gw   = (const float*)d_in[4];
  const float* temp = (const float*)d_in[5];
  const float* Wo   = (const float*)d_in[6];
  const float* bo   = (const float*)d_in[7];
  const float* ln1w = (const float*)d_in[8];
  const float* ln1b = (const float*)d_in[9];
  const float* ln2w = (const float*)d_in[10];
  const float* ln2b = (const float*)d_in[11];
  const float* W1   = (const float*)d_in[12];
  const float* b1   = (const float*)d_in[13];
  const float* W2   = (const float*)d_in[14];
  const float* b2   = (const float*)d_in[15];

  char* ws = (char*)d_ws;
  u16*  wqb  = (u16*)(ws + 0);
  u16*  wkb  = (u16*)(ws + 65536);
  u16*  wvb  = (u16*)(ws + 131072);
  u16*  wob  = (u16*)(ws + 196608);
  u16*  w1b  = (u16*)(ws + 720896);
  u16*  w2b  = (u16*)(ws + 2818048);
  u16*  h1b  = (u16*)(ws + 4915200);
  u16*  qb   = (u16*)(ws + 9109504);
  u16*  kb   = (u16*)(ws + 13303808);
  u16*  vtb  = (u16*)(ws + 17498112);
  float* qsq = (float*)(ws + 21692416);
  float* ksq = (float*)(ws + 21823488);
  float* qrs = (float*)(ws + 21954560);
  float* krs = (float*)(ws + 22085632);
  u16*  attnb= (u16*)(ws + 22478848);
  float* x1  = (float*)(ws + 26673152);
  u16*  h2b  = (u16*)(ws + 35061760);
  float* p1f = (float*)(ws + 35061760);  // aliases h2b (dead after FF1) + 4.2MB beyond
  u16*  gb   = (u16*)(ws + 4915200);     // aliases h1b/qb/kb/vtb (dead before FF1)

  float* outf = (float*)d_out;
  float* wout = outf + 4096*512;

  convert_weights<<<2400, 256, 0, stream>>>(Wq, Wk, Wv, Wo, W1, W2,
                                            wqb, wkb, wvb, wob, w1b, w2b);
  ln_kernel<<<4096, 128, 0, stream>>>(x, ln1w, ln1b, h1b);
  qkv_kernel<<<dim3(64, 8), 256, 0, stream>>>(h1b, wqb, wkb, wvb, qb, kb, vtb,
                                              qsq, qrs, ksq, krs);
  attn_kernel<<<dim3(32, 32), 512, 0, stream>>>(qb, kb, vtb, qsq, qrs,
                                                ksq, krs, gw, temp, attnb);
  gemm_kernel<512, 512, 64, 0><<<dim3(64, 8), 256, 0, stream>>>(
      attnb, wob, bo, x, x1, nullptr, nullptr, nullptr, nullptr);
  ln_kernel<<<4096, 128, 0, stream>>>(x1, ln2w, ln2b, h2b);
  gemm_kernel<512, 512, 128, 1><<<dim3(64, 16), 256, 0, stream>>>(
      h2b, w1b, b1, nullptr, nullptr, nullptr, gb, nullptr, nullptr);
  gemm_kernel<1024, 2048, 64, 3><<<dim3(64, 8, 2), 256, 0, stream>>>(
      gb, w2b, nullptr, nullptr, outf, p1f, nullptr, nullptr, nullptr);
  ff2_combine<<<2048, 256, 0, stream>>>(outf, p1f, b2, x1, outf, gw, wout);
}